// Round 1
// baseline (6906.896 us; speedup 1.0000x reference)
//
#include <hip/hip_runtime.h>
#include <cstdint>
#include <climits>

// Problem constants (fixed by setup_inputs)
constexpr int kB = 2;
constexpr int kN = 100;
constexpr int kH = 640;
constexpr int kW = 640;
constexpr int kHW = kH * kW;          // 409600
constexpr int kWORDS = kHW / 64;      // 6400 u64 words per mask
constexpr int kD = 384;
constexpr int kFH = 40;
constexpr int kFW = 40;
constexpr int kC = 80;
constexpr int kC1 = kC + 1;           // 81
constexpr int kTOPK = 40;

constexpr float MASK_THRESH = 0.4f;
constexpr float SCORE_THRESH = 0.35f;
constexpr float SUPPRESS_IOU = 0.85f;

// Output layout (concatenated flat, reference return order)
constexpr size_t O_MASK = 0;
constexpr size_t O_CLS  = (size_t)kB * kN * kHW;          // 81,920,000
constexpr size_t O_BOX  = O_CLS + (size_t)kB * kN * kC1;  // +16,200
constexpr size_t O_EMB  = O_BOX + (size_t)kB * kN * 4;    // +800

__device__ __forceinline__ float logitf_(float p) {
    p = fminf(fmaxf(p, 1e-4f), 1.0f - 1e-4f);
    return logf(p) - log1pf(-p);
}

// ---------------------------------------------------------------------------
// K0: per-image argsort by descending score (stable), init area/bbox arrays.
// grid(kB), block(128)
__global__ void k0_sort_init(const float* __restrict__ scores,
                             const int* __restrict__ labels,
                             int* __restrict__ order, float* __restrict__ sScore,
                             int* __restrict__ sLabel, int* __restrict__ area,
                             int* __restrict__ bbox) {
    int b = blockIdx.x;
    int t = threadIdx.x;
    if (t < kN) {
        float si = scores[b * kN + t];
        int rank = 0;
        for (int j = 0; j < kN; ++j) {
            float sj = scores[b * kN + j];
            if (sj > si || (sj == si && j < t)) rank++;
        }
        order[b * kN + rank]  = t;
        sScore[b * kN + rank] = si;
        sLabel[b * kN + rank] = labels[b * kN + t];
        area[b * kN + t] = 0;
        bbox[(b * kN + t) * 4 + 0] = INT_MAX;  // xmin
        bbox[(b * kN + t) * 4 + 1] = INT_MIN;  // xmax
        bbox[(b * kN + t) * 4 + 2] = INT_MAX;  // ymin
        bbox[(b * kN + t) * 4 + 3] = INT_MIN;  // ymax
    }
}

// ---------------------------------------------------------------------------
// K1: bit-pack thresholded masks (sorted order) + area + bbox.
// grid(SPLIT=8, kN, kB), block(256). Each wave packs via __ballot: the 64-bit
// ballot result is exactly the packed word in pixel order.
constexpr int kSPLIT = 8;
__global__ __launch_bounds__(256) void k1_pack(
    const float* __restrict__ masks, const int* __restrict__ order,
    unsigned long long* __restrict__ packed, int* __restrict__ area,
    int* __restrict__ bbox) {
    int b = blockIdx.z, slot = blockIdx.y;
    int q = order[b * kN + slot];
    const float* src = masks + (size_t)(b * kN + q) * kHW;
    unsigned long long* dst = packed + (size_t)(b * kN + slot) * (size_t)kWORDS;
    int lane = threadIdx.x & 63;
    int wv = threadIdx.x >> 6;
    const int wordsPerBlock = kWORDS / kSPLIT;  // 800
    const int wordsPerWave = wordsPerBlock / 4; // 200
    int wbase = blockIdx.x * wordsPerBlock + wv * wordsPerWave;

    int areaAcc = 0;
    int x1 = INT_MAX, x2 = INT_MIN, y1 = INT_MAX, y2 = INT_MIN;
    for (int i = 0; i < wordsPerWave; ++i) {
        int w = wbase + i;
        float v = src[(size_t)w * 64 + lane];
        bool pred = v > MASK_THRESH;
        unsigned long long m = __ballot(pred);
        areaAcc += pred ? 1 : 0;
        if (lane == 0) {
            dst[w] = m;
            if (m) {
                int row  = w / 10;             // 640/64 = 10 words per row
                int col0 = (w % 10) * 64;
                int lo = col0 + (__ffsll((unsigned long long)m) - 1);
                int hi = col0 + 63 - __clzll((long long)m);
                x1 = min(x1, lo); x2 = max(x2, hi);
                y1 = min(y1, row); y2 = max(y2, row);
            }
        }
    }
    __shared__ int sA[256];
    __shared__ int sx1[4], sx2[4], sy1[4], sy2[4];
    sA[threadIdx.x] = areaAcc;
    if (lane == 0) { sx1[wv] = x1; sx2[wv] = x2; sy1[wv] = y1; sy2[wv] = y2; }
    __syncthreads();
    for (int s = 128; s > 0; s >>= 1) {
        if (threadIdx.x < s) sA[threadIdx.x] += sA[threadIdx.x + s];
        __syncthreads();
    }
    if (threadIdx.x == 0) {
        atomicAdd(&area[b * kN + slot], sA[0]);
        int bx1 = min(min(sx1[0], sx1[1]), min(sx1[2], sx1[3]));
        int bx2 = max(max(sx2[0], sx2[1]), max(sx2[2], sx2[3]));
        int by1 = min(min(sy1[0], sy1[1]), min(sy1[2], sy1[3]));
        int by2 = max(max(sy2[0], sy2[1]), max(sy2[2], sy2[3]));
        if (bx1 != INT_MAX) {
            atomicMin(&bbox[(b * kN + slot) * 4 + 0], bx1);
            atomicMax(&bbox[(b * kN + slot) * 4 + 1], bx2);
            atomicMin(&bbox[(b * kN + slot) * 4 + 2], by1);
            atomicMax(&bbox[(b * kN + slot) * 4 + 3], by2);
        }
    }
}

// ---------------------------------------------------------------------------
// K2a: conflict matrix (lower triangle). grid(kN, kN, kB), block(256).
// Most blocks exit immediately (j>=i or label mismatch).
__global__ __launch_bounds__(256) void k2a_conflict(
    const unsigned long long* __restrict__ packed,
    const int* __restrict__ sLabel, const int* __restrict__ area,
    unsigned char* __restrict__ conflict) {
    int i = blockIdx.x, j = blockIdx.y, b = blockIdx.z;
    if (j >= i) return;
    if (sLabel[b * kN + i] != sLabel[b * kN + j]) {
        if (threadIdx.x == 0) conflict[(size_t)(b * kN + i) * kN + j] = 0;
        return;
    }
    const unsigned long long* pi = packed + (size_t)(b * kN + i) * kWORDS;
    const unsigned long long* pj = packed + (size_t)(b * kN + j) * kWORDS;
    int acc = 0;
    for (int w = threadIdx.x; w < kWORDS; w += 256)
        acc += __popcll(pi[w] & pj[w]);
    __shared__ int s[256];
    s[threadIdx.x] = acc;
    __syncthreads();
    for (int st = 128; st > 0; st >>= 1) {
        if (threadIdx.x < st) s[threadIdx.x] += s[threadIdx.x + st];
        __syncthreads();
    }
    if (threadIdx.x == 0) {
        float inter = (float)s[0];
        float un = fmaxf((float)area[b * kN + i] + (float)area[b * kN + j] - inter, 1.0f);
        conflict[(size_t)(b * kN + i) * kN + j] = (inter / un >= SUPPRESS_IOU) ? 1 : 0;
    }
}

// ---------------------------------------------------------------------------
// K2b: sequential greedy keep (exactly mirrors the fori_loop). grid(kB).
__global__ void k2b_greedy(const float* __restrict__ sScore,
                           const int* __restrict__ order,
                           const unsigned char* __restrict__ conflict,
                           int* __restrict__ src_q, int* __restrict__ keep_s,
                           int* __restrict__ countArr) {
    int b = blockIdx.x;
    if (threadIdx.x != 0) return;
    bool kept[kN];
    bool stopped = false;
    int count = 0;
    for (int i = 0; i < kN; ++i) {
        if (sScore[b * kN + i] < SCORE_THRESH) stopped = true;
        bool clash = false;
        for (int j = 0; j < i; ++j) {
            if (kept[j] && conflict[(size_t)(b * kN + i) * kN + j]) { clash = true; break; }
        }
        bool take = (!stopped) && (!clash);
        kept[i] = take;
        if (take) {
            src_q[b * kN + count]  = order[b * kN + i];
            keep_s[b * kN + count] = i;
            count++;
            if (count >= kTOPK) stopped = true;
        }
    }
    countArr[b] = count;
    for (int s = count; s < kN; ++s) { src_q[b * kN + s] = -1; keep_s[b * kN + s] = -1; }
}

// ---------------------------------------------------------------------------
// K3: mask_logits. grid(kHW/1024=400, kN, kB), block(256), float4.
__global__ __launch_bounds__(256) void k3_mask_logits(
    const float* __restrict__ masks, const int* __restrict__ src_q,
    float* __restrict__ out) {
    int b = blockIdx.z, slot = blockIdx.y;
    int q = src_q[b * kN + slot];
    size_t p4 = (size_t)blockIdx.x * 256 + threadIdx.x;
    float4 v;
    if (q >= 0) {
        const float4* src = (const float4*)(masks + (size_t)(b * kN + q) * kHW);
        float4 m = src[p4];
        v.x = logitf_(m.x); v.y = logitf_(m.y); v.z = logitf_(m.z); v.w = logitf_(m.w);
    } else {
        v = make_float4(-20.f, -20.f, -20.f, -20.f);
    }
    float4* dst = (float4*)(out + O_MASK + (size_t)(b * kN + slot) * kHW);
    dst[p4] = v;
}

// ---------------------------------------------------------------------------
// K4: class_logits + boxes. grid(kB), block(256).
__global__ void k4_cls_box(const float* __restrict__ sScore,
                           const int* __restrict__ sLabel,
                           const int* __restrict__ keep_s,
                           const int* __restrict__ countArr,
                           const int* __restrict__ area,
                           const int* __restrict__ bbox,
                           float* __restrict__ out) {
    int b = blockIdx.x;
    int count = countArr[b];
    for (int e = threadIdx.x; e < kN * kC1; e += 256) {
        int slot = e / kC1, c = e % kC1;
        float val = -10.0f;
        if (slot < count) {
            int s = keep_s[b * kN + slot];
            int lab = min(max(sLabel[b * kN + s], 0), kC - 1);
            float sc = fminf(fmaxf(sScore[b * kN + s], 0.f), 1.f);
            if (c == lab) val = logitf_(sc);
            else if (c == kC1 - 1) val = 0.0f;
        }
        out[O_CLS + (size_t)b * kN * kC1 + e] = val;
    }
    for (int slot = threadIdx.x; slot < kN; slot += 256) {
        float bx[4] = {0.f, 0.f, 0.f, 0.f};
        if (slot < count) {
            int s = keep_s[b * kN + slot];
            if (area[b * kN + s] > 0) {
                float x1 = (float)bbox[(b * kN + s) * 4 + 0];
                float x2 = (float)bbox[(b * kN + s) * 4 + 1];
                float y1 = (float)bbox[(b * kN + s) * 4 + 2];
                float y2 = (float)bbox[(b * kN + s) * 4 + 3];
                bx[0] = fminf(fmaxf((x1 + x2) * 0.5f / kW, 0.f), 1.f);
                bx[1] = fminf(fmaxf((y1 + y2) * 0.5f / kH, 0.f), 1.f);
                bx[2] = fminf(fmaxf(fmaxf(x2 - x1, 0.f) / kW, 0.f), 1.f);
                bx[3] = fminf(fmaxf(fmaxf(y2 - y1, 0.f) / kH, 0.f), 1.f);
            }
        }
        for (int c4 = 0; c4 < 4; ++c4)
            out[O_BOX + (size_t)(b * kN + slot) * 4 + c4] = bx[c4];
    }
}

// ---------------------------------------------------------------------------
// K5: antialiased linear resize along x (640 -> 40), kept masks only.
// jax.image.resize semantics: triangle kernel, kernel_scale=16,
// sample center = 16*ox + 7.5, taps max(0,16ox-8)..min(639,16ox+23),
// normalized by tap-weight sum (16 interior, 14 at edges).
// grid(160, kTOPK, kB), block(256): 4 rows/block, one wave per row, lane=ox.
__global__ __launch_bounds__(256) void k5_resize_x(
    const float* __restrict__ masks, const int* __restrict__ src_q,
    const int* __restrict__ countArr, float* __restrict__ S1) {
    int b = blockIdx.z, k = blockIdx.y;
    if (k >= countArr[b]) return;
    int q = src_q[b * kN + k];
    int lane = threadIdx.x & 63, wv = threadIdx.x >> 6;
    if (lane >= kFW) return;
    int y = blockIdx.x * 4 + wv;
    int ox = lane;
    const float* row = masks + (size_t)(b * kN + q) * kHW + (size_t)y * kW;
    float c = 16.0f * ox + 7.5f;
    int j0 = max(0, 16 * ox - 8), j1 = min(kW - 1, 16 * ox + 23);
    float s = 0.f;
    for (int j = j0; j <= j1; ++j) {
        float w = 1.0f - fabsf((float)j - c) * (1.0f / 16.0f);
        float m = fminf(fmaxf(row[j], 0.f), 1.f);  // masks_p = clip(masks,0,1)
        s += w * m;
    }
    float rs = (ox == 0 || ox == kFW - 1) ? (1.0f / 14.0f) : (1.0f / 16.0f);
    S1[((size_t)(b * kTOPK + k) * kH + y) * kFW + ox] = s * rs;
}

// ---------------------------------------------------------------------------
// K6: resize along y (640 -> 40) + per-mask sum (denominator).
// grid(kTOPK, kB), block(256).
__global__ __launch_bounds__(256) void k6_resize_y(
    const float* __restrict__ S1, const int* __restrict__ countArr,
    float* __restrict__ msmall, float* __restrict__ denom) {
    int k = blockIdx.x, b = blockIdx.y;
    if (k >= countArr[b]) return;
    const float* src = S1 + (size_t)(b * kTOPK + k) * kH * kFW;
    float tot = 0.f;
    for (int e = threadIdx.x; e < kFH * kFW; e += 256) {
        int oy = e / kFW, ox = e % kFW;
        float c = 16.0f * oy + 7.5f;
        int j0 = max(0, 16 * oy - 8), j1 = min(kH - 1, 16 * oy + 23);
        float s = 0.f;
        for (int j = j0; j <= j1; ++j) {
            float w = 1.0f - fabsf((float)j - c) * (1.0f / 16.0f);
            s += w * src[(size_t)j * kFW + ox];
        }
        float rs = (oy == 0 || oy == kFH - 1) ? (1.0f / 14.0f) : (1.0f / 16.0f);
        s *= rs;
        msmall[(size_t)(b * kTOPK + k) * kFH * kFW + e] = s;
        tot += s;
    }
    __shared__ float sm[256];
    sm[threadIdx.x] = tot;
    __syncthreads();
    for (int st = 128; st > 0; st >>= 1) {
        if (threadIdx.x < st) sm[threadIdx.x] += sm[threadIdx.x + st];
        __syncthreads();
    }
    if (threadIdx.x == 0) denom[b * kTOPK + k] = fmaxf(sm[0], 1e-6f);
}

// ---------------------------------------------------------------------------
// K7: mask-pooled features. grid(kD, kB), block(64). Each wave caches one
// feature channel (1600 floats = 25 regs/lane) and dots against all kept
// small-masks with a wave reduction.
__global__ __launch_bounds__(64) void k7_pool(
    const float* __restrict__ feat, const float* __restrict__ msmall,
    const float* __restrict__ denom, const int* __restrict__ countArr,
    float* __restrict__ pooled) {
    int d = blockIdx.x, b = blockIdx.y;
    int lane = threadIdx.x;
    const float* fp = feat + ((size_t)b * kD + d) * (kFH * kFW);
    float f[25];
#pragma unroll
    for (int i = 0; i < 25; ++i) f[i] = fp[i * 64 + lane];
    int count = countArr[b];
    for (int k = 0; k < count; ++k) {
        const float* sp = msmall + (size_t)(b * kTOPK + k) * (kFH * kFW);
        float acc = 0.f;
#pragma unroll
        for (int i = 0; i < 25; ++i) acc += f[i] * sp[i * 64 + lane];
        for (int off = 32; off > 0; off >>= 1) acc += __shfl_down(acc, off);
        if (lane == 0)
            pooled[(size_t)(b * kTOPK + k) * kD + d] = acc / denom[b * kTOPK + k];
    }
}

// ---------------------------------------------------------------------------
// K8: L2-normalize pooled -> embs (zeros for invalid). grid(kN, kB), block(128).
__global__ void k8_embs(const float* __restrict__ pooled,
                        const int* __restrict__ countArr,
                        float* __restrict__ out) {
    int slot = blockIdx.x, b = blockIdx.y;
    int count = countArr[b];
    float* dst = out + O_EMB + (size_t)(b * kN + slot) * kD;
    if (slot >= count) {
        for (int e = threadIdx.x; e < kD; e += 128) dst[e] = 0.f;
        return;
    }
    const float* p = pooled + (size_t)(b * kTOPK + slot) * kD;
    float ss = 0.f;
    for (int e = threadIdx.x; e < kD; e += 128) { float v = p[e]; ss += v * v; }
    __shared__ float sm[128];
    sm[threadIdx.x] = ss;
    __syncthreads();
    for (int st = 64; st > 0; st >>= 1) {
        if (threadIdx.x < st) sm[threadIdx.x] += sm[threadIdx.x + st];
        __syncthreads();
    }
    float norm = fmaxf(sqrtf(sm[0]), 1e-12f);
    for (int e = threadIdx.x; e < kD; e += 128) dst[e] = p[e] / norm;
}

// ---------------------------------------------------------------------------
extern "C" void kernel_launch(void* const* d_in, const int* in_sizes, int n_in,
                              void* d_out, int out_size, void* d_ws, size_t ws_size,
                              hipStream_t stream) {
    const float* masks  = (const float*)d_in[0];
    const int*   labels = (const int*)d_in[1];
    const float* scores = (const float*)d_in[2];
    const float* feat   = (const float*)d_in[3];
    // d_in[4] = class_count (device scalar) — fixed at 80 per problem shape.
    float* out = (float*)d_out;

    // Workspace carve-up (~19.1 MB total)
    char* ws = (char*)d_ws;
    auto take = [&](size_t bytes) { char* p = ws; ws += (bytes + 255) & ~(size_t)255; return p; };
    unsigned long long* packed = (unsigned long long*)take((size_t)kB * kN * kWORDS * 8);
    float* S1     = (float*)take((size_t)kB * kTOPK * kH * kFW * 4);
    float* msmall = (float*)take((size_t)kB * kTOPK * kFH * kFW * 4);
    float* pooled = (float*)take((size_t)kB * kTOPK * kD * 4);
    float* sScore = (float*)take((size_t)kB * kN * 4);
    float* denom  = (float*)take((size_t)kB * kTOPK * 4);
    int* order    = (int*)take((size_t)kB * kN * 4);
    int* sLabel   = (int*)take((size_t)kB * kN * 4);
    int* area     = (int*)take((size_t)kB * kN * 4);
    int* bbox     = (int*)take((size_t)kB * kN * 4 * 4);
    int* src_q    = (int*)take((size_t)kB * kN * 4);
    int* keep_s   = (int*)take((size_t)kB * kN * 4);
    int* countArr = (int*)take((size_t)kB * 4);
    unsigned char* conflict = (unsigned char*)take((size_t)kB * kN * kN);

    k0_sort_init<<<dim3(kB), dim3(128), 0, stream>>>(scores, labels, order, sScore,
                                                     sLabel, area, bbox);
    k1_pack<<<dim3(kSPLIT, kN, kB), dim3(256), 0, stream>>>(masks, order, packed,
                                                            area, bbox);
    k2a_conflict<<<dim3(kN, kN, kB), dim3(256), 0, stream>>>(packed, sLabel, area,
                                                             conflict);
    k2b_greedy<<<dim3(kB), dim3(64), 0, stream>>>(sScore, order, conflict, src_q,
                                                  keep_s, countArr);
    k3_mask_logits<<<dim3(kHW / 1024, kN, kB), dim3(256), 0, stream>>>(masks, src_q, out);
    k4_cls_box<<<dim3(kB), dim3(256), 0, stream>>>(sScore, sLabel, keep_s, countArr,
                                                   area, bbox, out);
    k5_resize_x<<<dim3(kH / 4, kTOPK, kB), dim3(256), 0, stream>>>(masks, src_q,
                                                                   countArr, S1);
    k6_resize_y<<<dim3(kTOPK, kB), dim3(256), 0, stream>>>(S1, countArr, msmall, denom);
    k7_pool<<<dim3(kD, kB), dim3(64), 0, stream>>>(feat, msmall, denom, countArr, pooled);
    k8_embs<<<dim3(kN, kB), dim3(128), 0, stream>>>(pooled, countArr, out);
}

// Round 2
// 947.953 us; speedup vs baseline: 7.2861x; 7.2861x over previous
//
#include <hip/hip_runtime.h>
#include <cstdint>
#include <climits>

// Problem constants (fixed by setup_inputs)
constexpr int kB = 2;
constexpr int kN = 100;
constexpr int kH = 640;
constexpr int kW = 640;
constexpr int kHW = kH * kW;          // 409600
constexpr int kWORDS = kHW / 64;      // 6400 u64 words per mask
constexpr int kD = 384;
constexpr int kFH = 40;
constexpr int kFW = 40;
constexpr int kC = 80;
constexpr int kC1 = kC + 1;           // 81
constexpr int kTOPK = 40;
constexpr int kCW = 2;                // conflict row words (ceil(100/64))

constexpr float MASK_THRESH = 0.4f;
constexpr float SCORE_THRESH = 0.35f;
constexpr float SUPPRESS_IOU = 0.85f;

// Output layout (concatenated flat, reference return order)
constexpr size_t O_MASK = 0;
constexpr size_t O_CLS  = (size_t)kB * kN * kHW;          // 81,920,000
constexpr size_t O_BOX  = O_CLS + (size_t)kB * kN * kC1;  // +16,200
constexpr size_t O_EMB  = O_BOX + (size_t)kB * kN * 4;    // +800

__device__ __forceinline__ float logitf_(float p) {
    p = fminf(fmaxf(p, 1e-4f), 1.0f - 1e-4f);
    return logf(p) - log1pf(-p);
}

// ---------------------------------------------------------------------------
// K0: per-image argsort by descending score (stable), init area/bbox/confRow.
// grid(kB), block(128)
__global__ void k0_sort_init(const float* __restrict__ scores,
                             const int* __restrict__ labels,
                             int* __restrict__ order, float* __restrict__ sScore,
                             int* __restrict__ sLabel, int* __restrict__ area,
                             int* __restrict__ bbox,
                             unsigned long long* __restrict__ confRow) {
    int b = blockIdx.x;
    int t = threadIdx.x;
    if (t < kN) {
        float si = scores[b * kN + t];
        int rank = 0;
        for (int j = 0; j < kN; ++j) {
            float sj = scores[b * kN + j];
            if (sj > si || (sj == si && j < t)) rank++;
        }
        order[b * kN + rank]  = t;
        sScore[b * kN + rank] = si;
        sLabel[b * kN + rank] = labels[b * kN + t];
        area[b * kN + t] = 0;
        bbox[(b * kN + t) * 4 + 0] = INT_MAX;  // xmin
        bbox[(b * kN + t) * 4 + 1] = INT_MIN;  // xmax
        bbox[(b * kN + t) * 4 + 2] = INT_MAX;  // ymin
        bbox[(b * kN + t) * 4 + 3] = INT_MIN;  // ymax
        confRow[(b * kN + t) * kCW + 0] = 0ull;
        confRow[(b * kN + t) * kCW + 1] = 0ull;
    }
}

// ---------------------------------------------------------------------------
// K1: bit-pack thresholded masks (sorted order) + area + bbox.
// grid(SPLIT=8, kN, kB), block(256). Each wave packs via __ballot: the 64-bit
// ballot result is exactly the packed word in pixel order.
constexpr int kSPLIT = 8;
__global__ __launch_bounds__(256) void k1_pack(
    const float* __restrict__ masks, const int* __restrict__ order,
    unsigned long long* __restrict__ packed, int* __restrict__ area,
    int* __restrict__ bbox) {
    int b = blockIdx.z, slot = blockIdx.y;
    int q = order[b * kN + slot];
    const float* src = masks + (size_t)(b * kN + q) * kHW;
    unsigned long long* dst = packed + (size_t)(b * kN + slot) * (size_t)kWORDS;
    int lane = threadIdx.x & 63;
    int wv = threadIdx.x >> 6;
    const int wordsPerBlock = kWORDS / kSPLIT;  // 800
    const int wordsPerWave = wordsPerBlock / 4; // 200
    int wbase = blockIdx.x * wordsPerBlock + wv * wordsPerWave;

    int areaAcc = 0;
    int x1 = INT_MAX, x2 = INT_MIN, y1 = INT_MAX, y2 = INT_MIN;
    for (int i = 0; i < wordsPerWave; ++i) {
        int w = wbase + i;
        float v = src[(size_t)w * 64 + lane];
        bool pred = v > MASK_THRESH;
        unsigned long long m = __ballot(pred);
        areaAcc += pred ? 1 : 0;
        if (lane == 0) {
            dst[w] = m;
            if (m) {
                int row  = w / 10;             // 640/64 = 10 words per row
                int col0 = (w % 10) * 64;
                int lo = col0 + (__ffsll((unsigned long long)m) - 1);
                int hi = col0 + 63 - __clzll((long long)m);
                x1 = min(x1, lo); x2 = max(x2, hi);
                y1 = min(y1, row); y2 = max(y2, row);
            }
        }
    }
    __shared__ int sA[256];
    __shared__ int sx1[4], sx2[4], sy1[4], sy2[4];
    sA[threadIdx.x] = areaAcc;
    if (lane == 0) { sx1[wv] = x1; sx2[wv] = x2; sy1[wv] = y1; sy2[wv] = y2; }
    __syncthreads();
    for (int s = 128; s > 0; s >>= 1) {
        if (threadIdx.x < s) sA[threadIdx.x] += sA[threadIdx.x + s];
        __syncthreads();
    }
    if (threadIdx.x == 0) {
        atomicAdd(&area[b * kN + slot], sA[0]);
        int bx1 = min(min(sx1[0], sx1[1]), min(sx1[2], sx1[3]));
        int bx2 = max(max(sx2[0], sx2[1]), max(sx2[2], sx2[3]));
        int by1 = min(min(sy1[0], sy1[1]), min(sy1[2], sy1[3]));
        int by2 = max(max(sy2[0], sy2[1]), max(sy2[2], sy2[3]));
        if (bx1 != INT_MAX) {
            atomicMin(&bbox[(b * kN + slot) * 4 + 0], bx1);
            atomicMax(&bbox[(b * kN + slot) * 4 + 1], bx2);
            atomicMin(&bbox[(b * kN + slot) * 4 + 2], by1);
            atomicMax(&bbox[(b * kN + slot) * 4 + 3], by2);
        }
    }
}

// ---------------------------------------------------------------------------
// K2a: conflict bit-rows (lower triangle). grid(kN, kN, kB), block(256).
// Most blocks exit immediately (j>=i or label mismatch). Sets bit j in row i
// via atomicOr when IoU >= SUPPRESS_IOU.
__global__ __launch_bounds__(256) void k2a_conflict(
    const unsigned long long* __restrict__ packed,
    const int* __restrict__ sLabel, const int* __restrict__ area,
    unsigned long long* __restrict__ confRow) {
    int i = blockIdx.x, j = blockIdx.y, b = blockIdx.z;
    if (j >= i) return;
    if (sLabel[b * kN + i] != sLabel[b * kN + j]) return;
    const unsigned long long* pi = packed + (size_t)(b * kN + i) * kWORDS;
    const unsigned long long* pj = packed + (size_t)(b * kN + j) * kWORDS;
    int acc = 0;
    for (int w = threadIdx.x; w < kWORDS; w += 256)
        acc += __popcll(pi[w] & pj[w]);
    __shared__ int s[256];
    s[threadIdx.x] = acc;
    __syncthreads();
    for (int st = 128; st > 0; st >>= 1) {
        if (threadIdx.x < st) s[threadIdx.x] += s[threadIdx.x + st];
        __syncthreads();
    }
    if (threadIdx.x == 0) {
        float inter = (float)s[0];
        float un = fmaxf((float)area[b * kN + i] + (float)area[b * kN + j] - inter, 1.0f);
        if (inter / un >= SUPPRESS_IOU)
            atomicOr(&confRow[(b * kN + i) * kCW + (j >> 6)], 1ull << (j & 63));
    }
}

// ---------------------------------------------------------------------------
// K2b: sequential greedy keep, memory-free inner loop. grid(kB), block(64).
// Stage scores + conflict bit-rows into LDS; kept-set lives in two u64
// registers; lane 0 runs the 100-step serial loop (~3 LDS reads per step,
// ~120 cyc each — µs-scale, vs 6.4 ms for the global/scratch version).
__global__ void k2b_greedy(const float* __restrict__ sScore,
                           const int* __restrict__ order,
                           const unsigned long long* __restrict__ confRow,
                           int* __restrict__ src_q, int* __restrict__ keep_s,
                           int* __restrict__ countArr) {
    int b = blockIdx.x;
    int t = threadIdx.x;
    __shared__ float sc[kN];
    __shared__ int   ord[kN];
    __shared__ unsigned long long cr[kN * kCW];
    for (int e = t; e < kN; e += 64) {
        sc[e]  = sScore[b * kN + e];
        ord[e] = order[b * kN + e];
    }
    for (int e = t; e < kN * kCW; e += 64)
        cr[e] = confRow[(size_t)b * kN * kCW + e];
    __syncthreads();
    if (t != 0) return;

    unsigned long long keptLo = 0ull, keptHi = 0ull;
    bool stopped = false;
    int count = 0;
    for (int i = 0; i < kN; ++i) {
        if (sc[i] < SCORE_THRESH) stopped = true;
        unsigned long long cl = cr[i * kCW + 0] & keptLo;
        unsigned long long ch = cr[i * kCW + 1] & keptHi;
        bool take = (!stopped) && ((cl | ch) == 0ull);
        if (take) {
            if (i < 64) keptLo |= 1ull << i; else keptHi |= 1ull << (i - 64);
            src_q[b * kN + count]  = ord[i];
            keep_s[b * kN + count] = i;
            count++;
            if (count >= kTOPK) stopped = true;
        }
    }
    countArr[b] = count;
    for (int s = count; s < kN; ++s) { src_q[b * kN + s] = -1; keep_s[b * kN + s] = -1; }
}

// ---------------------------------------------------------------------------
// K3: mask_logits. grid(kHW/1024=400, kN, kB), block(256), float4.
__global__ __launch_bounds__(256) void k3_mask_logits(
    const float* __restrict__ masks, const int* __restrict__ src_q,
    float* __restrict__ out) {
    int b = blockIdx.z, slot = blockIdx.y;
    int q = src_q[b * kN + slot];
    size_t p4 = (size_t)blockIdx.x * 256 + threadIdx.x;
    float4 v;
    if (q >= 0) {
        const float4* src = (const float4*)(masks + (size_t)(b * kN + q) * kHW);
        float4 m = src[p4];
        v.x = logitf_(m.x); v.y = logitf_(m.y); v.z = logitf_(m.z); v.w = logitf_(m.w);
    } else {
        v = make_float4(-20.f, -20.f, -20.f, -20.f);
    }
    float4* dst = (float4*)(out + O_MASK + (size_t)(b * kN + slot) * kHW);
    dst[p4] = v;
}

// ---------------------------------------------------------------------------
// K4: class_logits + boxes. grid(kB), block(256).
__global__ void k4_cls_box(const float* __restrict__ sScore,
                           const int* __restrict__ sLabel,
                           const int* __restrict__ keep_s,
                           const int* __restrict__ countArr,
                           const int* __restrict__ area,
                           const int* __restrict__ bbox,
                           float* __restrict__ out) {
    int b = blockIdx.x;
    int count = countArr[b];
    for (int e = threadIdx.x; e < kN * kC1; e += 256) {
        int slot = e / kC1, c = e % kC1;
        float val = -10.0f;
        if (slot < count) {
            int s = keep_s[b * kN + slot];
            int lab = min(max(sLabel[b * kN + s], 0), kC - 1);
            float sc = fminf(fmaxf(sScore[b * kN + s], 0.f), 1.f);
            if (c == lab) val = logitf_(sc);
            else if (c == kC1 - 1) val = 0.0f;
        }
        out[O_CLS + (size_t)b * kN * kC1 + e] = val;
    }
    for (int slot = threadIdx.x; slot < kN; slot += 256) {
        float bx[4] = {0.f, 0.f, 0.f, 0.f};
        if (slot < count) {
            int s = keep_s[b * kN + slot];
            if (area[b * kN + s] > 0) {
                float x1 = (float)bbox[(b * kN + s) * 4 + 0];
                float x2 = (float)bbox[(b * kN + s) * 4 + 1];
                float y1 = (float)bbox[(b * kN + s) * 4 + 2];
                float y2 = (float)bbox[(b * kN + s) * 4 + 3];
                bx[0] = fminf(fmaxf((x1 + x2) * 0.5f / kW, 0.f), 1.f);
                bx[1] = fminf(fmaxf((y1 + y2) * 0.5f / kH, 0.f), 1.f);
                bx[2] = fminf(fmaxf(fmaxf(x2 - x1, 0.f) / kW, 0.f), 1.f);
                bx[3] = fminf(fmaxf(fmaxf(y2 - y1, 0.f) / kH, 0.f), 1.f);
            }
        }
        for (int c4 = 0; c4 < 4; ++c4)
            out[O_BOX + (size_t)(b * kN + slot) * 4 + c4] = bx[c4];
    }
}

// ---------------------------------------------------------------------------
// K5: antialiased linear resize along x (640 -> 40), kept masks only.
// jax.image.resize semantics: triangle kernel, kernel_scale=16,
// sample center = 16*ox + 7.5, taps max(0,16ox-8)..min(639,16ox+23),
// normalized by tap-weight sum (16 interior, 14 at edges).
// grid(160, kTOPK, kB), block(256): 4 rows/block, one wave per row, lane=ox.
__global__ __launch_bounds__(256) void k5_resize_x(
    const float* __restrict__ masks, const int* __restrict__ src_q,
    const int* __restrict__ countArr, float* __restrict__ S1) {
    int b = blockIdx.z, k = blockIdx.y;
    if (k >= countArr[b]) return;
    int q = src_q[b * kN + k];
    int lane = threadIdx.x & 63, wv = threadIdx.x >> 6;
    if (lane >= kFW) return;
    int y = blockIdx.x * 4 + wv;
    int ox = lane;
    const float* row = masks + (size_t)(b * kN + q) * kHW + (size_t)y * kW;
    float c = 16.0f * ox + 7.5f;
    int j0 = max(0, 16 * ox - 8), j1 = min(kW - 1, 16 * ox + 23);
    float s = 0.f;
    for (int j = j0; j <= j1; ++j) {
        float w = 1.0f - fabsf((float)j - c) * (1.0f / 16.0f);
        float m = fminf(fmaxf(row[j], 0.f), 1.f);  // masks_p = clip(masks,0,1)
        s += w * m;
    }
    float rs = (ox == 0 || ox == kFW - 1) ? (1.0f / 14.0f) : (1.0f / 16.0f);
    S1[((size_t)(b * kTOPK + k) * kH + y) * kFW + ox] = s * rs;
}

// ---------------------------------------------------------------------------
// K6: resize along y (640 -> 40) + per-mask sum (denominator).
// grid(kTOPK, kB), block(256).
__global__ __launch_bounds__(256) void k6_resize_y(
    const float* __restrict__ S1, const int* __restrict__ countArr,
    float* __restrict__ msmall, float* __restrict__ denom) {
    int k = blockIdx.x, b = blockIdx.y;
    if (k >= countArr[b]) return;
    const float* src = S1 + (size_t)(b * kTOPK + k) * kH * kFW;
    float tot = 0.f;
    for (int e = threadIdx.x; e < kFH * kFW; e += 256) {
        int oy = e / kFW, ox = e % kFW;
        float c = 16.0f * oy + 7.5f;
        int j0 = max(0, 16 * oy - 8), j1 = min(kH - 1, 16 * oy + 23);
        float s = 0.f;
        for (int j = j0; j <= j1; ++j) {
            float w = 1.0f - fabsf((float)j - c) * (1.0f / 16.0f);
            s += w * src[(size_t)j * kFW + ox];
        }
        float rs = (oy == 0 || oy == kFH - 1) ? (1.0f / 14.0f) : (1.0f / 16.0f);
        s *= rs;
        msmall[(size_t)(b * kTOPK + k) * kFH * kFW + e] = s;
        tot += s;
    }
    __shared__ float sm[256];
    sm[threadIdx.x] = tot;
    __syncthreads();
    for (int st = 128; st > 0; st >>= 1) {
        if (threadIdx.x < st) sm[threadIdx.x] += sm[threadIdx.x + st];
        __syncthreads();
    }
    if (threadIdx.x == 0) denom[b * kTOPK + k] = fmaxf(sm[0], 1e-6f);
}

// ---------------------------------------------------------------------------
// K7: mask-pooled features. grid(kD, kB), block(64). Each wave caches one
// feature channel (1600 floats = 25 regs/lane) and dots against all kept
// small-masks with a wave reduction.
__global__ __launch_bounds__(64) void k7_pool(
    const float* __restrict__ feat, const float* __restrict__ msmall,
    const float* __restrict__ denom, const int* __restrict__ countArr,
    float* __restrict__ pooled) {
    int d = blockIdx.x, b = blockIdx.y;
    int lane = threadIdx.x;
    const float* fp = feat + ((size_t)b * kD + d) * (kFH * kFW);
    float f[25];
#pragma unroll
    for (int i = 0; i < 25; ++i) f[i] = fp[i * 64 + lane];
    int count = countArr[b];
    for (int k = 0; k < count; ++k) {
        const float* sp = msmall + (size_t)(b * kTOPK + k) * (kFH * kFW);
        float acc = 0.f;
#pragma unroll
        for (int i = 0; i < 25; ++i) acc += f[i] * sp[i * 64 + lane];
        for (int off = 32; off > 0; off >>= 1) acc += __shfl_down(acc, off);
        if (lane == 0)
            pooled[(size_t)(b * kTOPK + k) * kD + d] = acc / denom[b * kTOPK + k];
    }
}

// ---------------------------------------------------------------------------
// K8: L2-normalize pooled -> embs (zeros for invalid). grid(kN, kB), block(128).
__global__ void k8_embs(const float* __restrict__ pooled,
                        const int* __restrict__ countArr,
                        float* __restrict__ out) {
    int slot = blockIdx.x, b = blockIdx.y;
    int count = countArr[b];
    float* dst = out + O_EMB + (size_t)(b * kN + slot) * kD;
    if (slot >= count) {
        for (int e = threadIdx.x; e < kD; e += 128) dst[e] = 0.f;
        return;
    }
    const float* p = pooled + (size_t)(b * kTOPK + slot) * kD;
    float ss = 0.f;
    for (int e = threadIdx.x; e < kD; e += 128) { float v = p[e]; ss += v * v; }
    __shared__ float sm[128];
    sm[threadIdx.x] = ss;
    __syncthreads();
    for (int st = 64; st > 0; st >>= 1) {
        if (threadIdx.x < st) sm[threadIdx.x] += sm[threadIdx.x + st];
        __syncthreads();
    }
    float norm = fmaxf(sqrtf(sm[0]), 1e-12f);
    for (int e = threadIdx.x; e < kD; e += 128) dst[e] = p[e] / norm;
}

// ---------------------------------------------------------------------------
extern "C" void kernel_launch(void* const* d_in, const int* in_sizes, int n_in,
                              void* d_out, int out_size, void* d_ws, size_t ws_size,
                              hipStream_t stream) {
    const float* masks  = (const float*)d_in[0];
    const int*   labels = (const int*)d_in[1];
    const float* scores = (const float*)d_in[2];
    const float* feat   = (const float*)d_in[3];
    // d_in[4] = class_count (device scalar) — fixed at 80 per problem shape.
    float* out = (float*)d_out;

    // Workspace carve-up (~19.1 MB total)
    char* ws = (char*)d_ws;
    auto take = [&](size_t bytes) { char* p = ws; ws += (bytes + 255) & ~(size_t)255; return p; };
    unsigned long long* packed = (unsigned long long*)take((size_t)kB * kN * kWORDS * 8);
    float* S1     = (float*)take((size_t)kB * kTOPK * kH * kFW * 4);
    float* msmall = (float*)take((size_t)kB * kTOPK * kFH * kFW * 4);
    float* pooled = (float*)take((size_t)kB * kTOPK * kD * 4);
    float* sScore = (float*)take((size_t)kB * kN * 4);
    float* denom  = (float*)take((size_t)kB * kTOPK * 4);
    int* order    = (int*)take((size_t)kB * kN * 4);
    int* sLabel   = (int*)take((size_t)kB * kN * 4);
    int* area     = (int*)take((size_t)kB * kN * 4);
    int* bbox     = (int*)take((size_t)kB * kN * 4 * 4);
    int* src_q    = (int*)take((size_t)kB * kN * 4);
    int* keep_s   = (int*)take((size_t)kB * kN * 4);
    int* countArr = (int*)take((size_t)kB * 4);
    unsigned long long* confRow = (unsigned long long*)take((size_t)kB * kN * kCW * 8);

    k0_sort_init<<<dim3(kB), dim3(128), 0, stream>>>(scores, labels, order, sScore,
                                                     sLabel, area, bbox, confRow);
    k1_pack<<<dim3(kSPLIT, kN, kB), dim3(256), 0, stream>>>(masks, order, packed,
                                                            area, bbox);
    k2a_conflict<<<dim3(kN, kN, kB), dim3(256), 0, stream>>>(packed, sLabel, area,
                                                             confRow);
    k2b_greedy<<<dim3(kB), dim3(64), 0, stream>>>(sScore, order, confRow, src_q,
                                                  keep_s, countArr);
    k3_mask_logits<<<dim3(kHW / 1024, kN, kB), dim3(256), 0, stream>>>(masks, src_q, out);
    k4_cls_box<<<dim3(kB), dim3(256), 0, stream>>>(sScore, sLabel, keep_s, countArr,
                                                   area, bbox, out);
    k5_resize_x<<<dim3(kH / 4, kTOPK, kB), dim3(256), 0, stream>>>(masks, src_q,
                                                                   countArr, S1);
    k6_resize_y<<<dim3(kTOPK, kB), dim3(256), 0, stream>>>(S1, countArr, msmall, denom);
    k7_pool<<<dim3(kD, kB), dim3(64), 0, stream>>>(feat, msmall, denom, countArr, pooled);
    k8_embs<<<dim3(kN, kB), dim3(128), 0, stream>>>(pooled, countArr, out);
}